// Round 1
// baseline (553.518 us; speedup 1.0000x reference)
//
#include <hip/hip_runtime.h>
#include <stdint.h>

#define DD 1024      // model dim
#define NH 16        // heads
#define DHEAD 64     // head dim
#define NB 4         // batch
#define SEQ 2048     // seq len
#define MR (NB*SEQ)  // 8192 rows

typedef __attribute__((ext_vector_type(8))) short s8v;
typedef __attribute__((ext_vector_type(4))) float f4v;

__device__ __forceinline__ unsigned short f2bf(float f) {
  union { float f; uint32_t u; } c; c.f = f;
  uint32_t u = c.u;
  u += 0x7fffu + ((u >> 16) & 1u);   // RNE
  return (unsigned short)(u >> 16);
}

__device__ __forceinline__ void load_lds16(const void* g, void* lds) {
  __builtin_amdgcn_global_load_lds(
      (__attribute__((address_space(1))) void*)(uintptr_t)g,
      (__attribute__((address_space(3))) void*)(uint32_t)(uintptr_t)lds,
      16, 0, 0);
}

// ---------------- fp32 -> bf16 convert (8 elems/thread) ----------------
__global__ void cvt8(const float* __restrict__ src, unsigned short* __restrict__ dst, int n) {
  int i = (blockIdx.x * 256 + threadIdx.x) * 8;
  if (i >= n) return;
  float4 a = *(const float4*)(src + i);
  float4 b = *(const float4*)(src + i + 4);
  union { unsigned short us[8]; uint4 u; } t;
  t.us[0] = f2bf(a.x); t.us[1] = f2bf(a.y); t.us[2] = f2bf(a.z); t.us[3] = f2bf(a.w);
  t.us[4] = f2bf(b.x); t.us[5] = f2bf(b.y); t.us[6] = f2bf(b.z); t.us[7] = f2bf(b.w);
  *(uint4*)(dst + i) = t.u;
}

// ---------------- GEMM: C[m,n] = sum_k A[m,k]*B[n,k] + bias[n] ----------------
// A: [M,K] bf16 row-major, B: [N,K] bf16 row-major (i.e. X @ W^T with torch W)
// 128x128 tile, BK=64, 4 waves (2x2 of 64x64), 16x16x32 MFMA, m97 structure.
template<int OUTBF>
__global__ __launch_bounds__(256, 2) void gemm_bt(
    const unsigned short* __restrict__ A,
    const unsigned short* __restrict__ Bw,
    const float* __restrict__ bias,
    void* __restrict__ Cout,
    int Mdim, int Ndim, int Kdim)
{
  __shared__ __align__(16) short As[128 * 64];
  __shared__ __align__(16) short Bs[128 * 64];
  const int tid = threadIdx.x;
  const int wave = tid >> 6, lane = tid & 63;
  const int wm = (wave >> 1) * 64, wn = (wave & 1) * 64;
  const int lr = lane & 15, lg = lane >> 4;
  const unsigned short* Ab = A + (size_t)blockIdx.y * 128 * Kdim;
  const unsigned short* Bb = Bw + (size_t)blockIdx.x * 128 * Kdim;

  f4v z = {0.f, 0.f, 0.f, 0.f};
  f4v acc[4][4];
  for (int mi = 0; mi < 4; mi++) for (int ni = 0; ni < 4; ni++) acc[mi][ni] = z;

  for (int k0 = 0; k0 < Kdim; k0 += 64) {
    __syncthreads();   // previous compute done before overwriting LDS
    for (int i = 0; i < 4; i++) {
      int c = tid + i * 256;            // chunk 0..1023, 8 bf16 per chunk
      int row = c >> 3, kc = (c & 7) << 3;
      load_lds16(Ab + (size_t)row * Kdim + k0 + kc, As + c * 8);
      load_lds16(Bb + (size_t)row * Kdim + k0 + kc, Bs + c * 8);
    }
    __syncthreads();   // drains vmcnt -> LDS valid
    for (int kk = 0; kk < 64; kk += 32) {
      s8v af[4], bf[4];
      for (int i = 0; i < 4; i++)
        af[i] = *(const s8v*)(As + (wm + i * 16 + lr) * 64 + kk + lg * 8);
      for (int i = 0; i < 4; i++)
        bf[i] = *(const s8v*)(Bs + (wn + i * 16 + lr) * 64 + kk + lg * 8);
      for (int mi = 0; mi < 4; mi++)
        for (int ni = 0; ni < 4; ni++)
          acc[mi][ni] = __builtin_amdgcn_mfma_f32_16x16x32_bf16(af[mi], bf[ni], acc[mi][ni], 0, 0, 0);
    }
  }
  // epilogue: C/D layout col=lane&15, row=(lane>>4)*4+r  (verified m89/m91)
  for (int ni = 0; ni < 4; ni++) {
    int col = blockIdx.x * 128 + wn + ni * 16 + lr;
    float bv = bias[col];
    for (int mi = 0; mi < 4; mi++) {
      int row0 = blockIdx.y * 128 + wm + mi * 16 + lg * 4;
      for (int r = 0; r < 4; r++) {
        float val = acc[mi][ni][r] + bv;
        if (OUTBF)
          ((unsigned short*)Cout)[(size_t)(row0 + r) * Ndim + col] = f2bf(val);
        else
          ((float*)Cout)[(size_t)(row0 + r) * Ndim + col] = val;
      }
    }
  }
}

// ---------------- causal flash attention ----------------
// Q,K,V in [B, L, H, DK] bf16 (row-major [8192,1024]); O same layout.
// grid: (SEQ/128, NB*NH); block 256 = 4 waves; wave owns 32 Q rows.
__global__ __launch_bounds__(256, 2) void fattn(
    const unsigned short* __restrict__ Qp,
    const unsigned short* __restrict__ Kp,
    const unsigned short* __restrict__ Vp,
    unsigned short* __restrict__ Op)
{
  __shared__ __align__(16) short Ks[64 * 64];     // K tile [c][d]
  __shared__ __align__(16) short Vt[64 * 72];     // V^T tile [d][c], padded
  __shared__ __align__(16) short Ps[4 * 32 * 72]; // per-wave P [r][c], padded
  const int tid = threadIdx.x;
  const int wave = tid >> 6, lane = tid & 63;
  const int lr = lane & 15, lg = lane >> 4;
  const int bh = blockIdx.y;
  const int b = bh >> 4, h = bh & 15;
  const int qbase = blockIdx.x * 128 + wave * 32;
  const unsigned short* Qrow = Qp + ((size_t)b * SEQ) * DD + h * DHEAD;
  const unsigned short* Krow = Kp + ((size_t)b * SEQ) * DD + h * DHEAD;
  const unsigned short* Vrow = Vp + ((size_t)b * SEQ) * DD + h * DHEAD;

  // Q fragments, kept in registers all kernel: A-layout A[m=lane&15][k=lg*8+j]
  s8v qf[2][2];
  for (int mi = 0; mi < 2; mi++)
    for (int ks = 0; ks < 2; ks++)
      qf[mi][ks] = *(const s8v*)(Qrow + (size_t)(qbase + mi * 16 + lr) * DD + ks * 32 + lg * 8);

  f4v zv = {0.f, 0.f, 0.f, 0.f};
  f4v o[2][4];
  float m2[2][4], lsum[2][4];
  for (int mi = 0; mi < 2; mi++)
    for (int r = 0; r < 4; r++) { m2[mi][r] = -1e30f; lsum[mi][r] = 0.f; }
  for (int mi = 0; mi < 2; mi++) for (int ni = 0; ni < 4; ni++) o[mi][ni] = zv;

  const float csc = 0.125f * 1.44269504089f;  // (1/sqrt(64)) * log2(e)
  const int ntiles = 2 * blockIdx.x + 2;

  for (int kt = 0; kt < ntiles; kt++) {
    __syncthreads();
    // stage K tile (64x64) via async global->LDS
    for (int i = 0; i < 2; i++) {
      int c = tid + i * 256;
      int row = c >> 3, kc = (c & 7) << 3;
      load_lds16(Krow + (size_t)(kt * 64 + row) * DD + kc, Ks + c * 8);
    }
    // stage V^T (transpose in flight), padded stride 72
    {
      int c = tid >> 2, dbase = (tid & 3) << 4;
      const unsigned short* vsrc = Vrow + (size_t)(kt * 64 + c) * DD + dbase;
      for (int half = 0; half < 2; half++) {
        s8v vv = *(const s8v*)(vsrc + half * 8);
        for (int j = 0; j < 8; j++)
          Vt[(dbase + half * 8 + j) * 72 + c] = vv[j];
      }
    }
    __syncthreads();

    if (kt * 64 <= qbase + 31) {   // wave-uniform causal participation
      // S = Q K^T  (raw dot; scale later)
      f4v s[2][4];
      for (int mi = 0; mi < 2; mi++) for (int ni = 0; ni < 4; ni++) s[mi][ni] = zv;
      for (int ks = 0; ks < 2; ks++) {
        s8v kf[4];
        for (int ni = 0; ni < 4; ni++)
          kf[ni] = *(const s8v*)(Ks + (ni * 16 + lr) * 64 + ks * 32 + lg * 8);
        for (int mi = 0; mi < 2; mi++)
          for (int ni = 0; ni < 4; ni++)
            s[mi][ni] = __builtin_amdgcn_mfma_f32_16x16x32_bf16(qf[mi][ks], kf[ni], s[mi][ni], 0, 0, 0);
      }
      // scale (base-2 domain) + causal mask on diagonal tiles
      const int colbase = kt * 64;
      const bool diag = (colbase + 63 > qbase);
      for (int mi = 0; mi < 2; mi++)
        for (int ni = 0; ni < 4; ni++)
          for (int r = 0; r < 4; r++) {
            float t = s[mi][ni][r] * csc;
            if (diag) {
              int row = qbase + mi * 16 + lg * 4 + r;
              int col = colbase + ni * 16 + lr;
              if (col > row) t = -1e9f;
            }
            s[mi][ni][r] = t;
          }
      // online softmax per row (rows live across 16 lanes of each quad-group)
      for (int mi = 0; mi < 2; mi++)
        for (int r = 0; r < 4; r++) {
          float mx = fmaxf(fmaxf(s[mi][0][r], s[mi][1][r]), fmaxf(s[mi][2][r], s[mi][3][r]));
          for (int d2 = 1; d2 < 16; d2 <<= 1) mx = fmaxf(mx, __shfl_xor(mx, d2));
          float mn = fmaxf(m2[mi][r], mx);
          float al = __builtin_amdgcn_exp2f(m2[mi][r] - mn);
          float ps = 0.f;
          for (int ni = 0; ni < 4; ni++) {
            float pp = __builtin_amdgcn_exp2f(s[mi][ni][r] - mn);
            s[mi][ni][r] = pp;
            ps += pp;
          }
          for (int d2 = 1; d2 < 16; d2 <<= 1) ps += __shfl_xor(ps, d2);
          lsum[mi][r] = lsum[mi][r] * al + ps;
          m2[mi][r] = mn;
          for (int ni = 0; ni < 4; ni++) o[mi][ni][r] *= al;
        }
      // P -> LDS (C-layout scatter) then re-read as A-operand
      short* Pw = Ps + wave * (32 * 72);
      for (int mi = 0; mi < 2; mi++)
        for (int ni = 0; ni < 4; ni++)
          for (int r = 0; r < 4; r++)
            Pw[(mi * 16 + lg * 4 + r) * 72 + ni * 16 + lr] = (short)f2bf(s[mi][ni][r]);
      // O += P V
      for (int kc2 = 0; kc2 < 2; kc2++) {
        s8v pf[2], vf[4];
        for (int mi = 0; mi < 2; mi++)
          pf[mi] = *(const s8v*)(Pw + (mi * 16 + lr) * 72 + kc2 * 32 + lg * 8);
        for (int ni = 0; ni < 4; ni++)
          vf[ni] = *(const s8v*)(Vt + (ni * 16 + lr) * 72 + kc2 * 32 + lg * 8);
        for (int mi = 0; mi < 2; mi++)
          for (int ni = 0; ni < 4; ni++)
            o[mi][ni] = __builtin_amdgcn_mfma_f32_16x16x32_bf16(pf[mi], vf[ni], o[mi][ni], 0, 0, 0);
      }
    }
  }

  // epilogue: O /= l, store bf16 to [B,L,H,DK]
  unsigned short* Orow = Op + ((size_t)b * SEQ) * DD + h * DHEAD;
  for (int mi = 0; mi < 2; mi++)
    for (int r = 0; r < 4; r++) {
      float inv = 1.f / lsum[mi][r];
      size_t row = (size_t)qbase + mi * 16 + lg * 4 + r;
      for (int ni = 0; ni < 4; ni++)
        Orow[row * DD + ni * 16 + lr] = f2bf(o[mi][ni][r] * inv);
    }
}

// ---------------- launcher ----------------
extern "C" void kernel_launch(void* const* d_in, const int* in_sizes, int n_in,
                              void* d_out, int out_size, void* d_ws, size_t ws_size,
                              hipStream_t stream) {
  const float* q    = (const float*)d_in[0];
  const float* k    = (const float*)d_in[1];
  const float* v    = (const float*)d_in[2];
  const float* wq_w = (const float*)d_in[3];
  const float* wq_b = (const float*)d_in[4];
  const float* wk_w = (const float*)d_in[5];
  const float* wk_b = (const float*)d_in[6];
  const float* wv_w = (const float*)d_in[7];
  const float* wv_b = (const float*)d_in[8];
  const float* wo_w = (const float*)d_in[9];
  const float* wo_b = (const float*)d_in[10];

  const size_t BIG = (size_t)MR * DD;   // 8.39M elems
  const size_t WSZ = (size_t)DD * DD;   // 1.05M elems
  unsigned short* p = (unsigned short*)d_ws;
  unsigned short* qb  = p; p += BIG;
  unsigned short* kb  = p; p += BIG;
  unsigned short* vb  = p; p += BIG;
  unsigned short* wqb = p; p += WSZ;
  unsigned short* wkb = p; p += WSZ;
  unsigned short* wvb = p; p += WSZ;
  unsigned short* wob = p; p += WSZ;
  unsigned short* Qp  = p; p += BIG;
  unsigned short* Kp  = p; p += BIG;
  unsigned short* Vp  = p; p += BIG;
  unsigned short* AO  = p; p += BIG;

  // converts
  cvt8<<<dim3(BIG / 8 / 256), dim3(256), 0, stream>>>(q, qb, (int)BIG);
  cvt8<<<dim3(BIG / 8 / 256), dim3(256), 0, stream>>>(k, kb, (int)BIG);
  cvt8<<<dim3(BIG / 8 / 256), dim3(256), 0, stream>>>(v, vb, (int)BIG);
  cvt8<<<dim3(WSZ / 8 / 256), dim3(256), 0, stream>>>(wq_w, wqb, (int)WSZ);
  cvt8<<<dim3(WSZ / 8 / 256), dim3(256), 0, stream>>>(wk_w, wkb, (int)WSZ);
  cvt8<<<dim3(WSZ / 8 / 256), dim3(256), 0, stream>>>(wv_w, wvb, (int)WSZ);
  cvt8<<<dim3(WSZ / 8 / 256), dim3(256), 0, stream>>>(wo_w, wob, (int)WSZ);

  // projections -> bf16 [B,L,H,DK]
  dim3 gg(DD / 128, MR / 128);
  gemm_bt<1><<<gg, dim3(256), 0, stream>>>(qb, wqb, wq_b, Qp, MR, DD, DD);
  gemm_bt<1><<<gg, dim3(256), 0, stream>>>(kb, wkb, wk_b, Kp, MR, DD, DD);
  gemm_bt<1><<<gg, dim3(256), 0, stream>>>(vb, wvb, wv_b, Vp, MR, DD, DD);

  // causal flash attention
  fattn<<<dim3(SEQ / 128, NB * NH), dim3(256), 0, stream>>>(Qp, Kp, Vp, AO);

  // output projection -> fp32 d_out
  gemm_bt<0><<<gg, dim3(256), 0, stream>>>(AO, wob, wo_b, (float*)d_out, MR, DD, DD);

  (void)in_sizes; (void)n_in; (void)out_size; (void)ws_size;
}

// Round 2
// 409.805 us; speedup vs baseline: 1.3507x; 1.3507x over previous
//
#include <hip/hip_runtime.h>
#include <stdint.h>

#define DD 1024      // model dim
#define NH 16        // heads
#define DHEAD 64     // head dim
#define NB 4         // batch
#define SEQ 2048     // seq len
#define MR (NB*SEQ)  // 8192 rows
#define NT (SEQ/128) // 16 Q-tiles of 128 rows

typedef __attribute__((ext_vector_type(8))) short s8v;
typedef __attribute__((ext_vector_type(4))) float f4v;

__device__ __forceinline__ unsigned short f2bf(float f) {
  union { float f; uint32_t u; } c; c.f = f;
  uint32_t u = c.u;
  u += 0x7fffu + ((u >> 16) & 1u);   // RNE
  return (unsigned short)(u >> 16);
}

__device__ __forceinline__ void load_lds16(const void* g, void* lds) {
  __builtin_amdgcn_global_load_lds(
      (__attribute__((address_space(1))) void*)(uintptr_t)g,
      (__attribute__((address_space(3))) void*)(uint32_t)(uintptr_t)lds,
      16, 0, 0);
}

// ---------------- fp32 -> bf16 convert (8 elems/thread) ----------------
__global__ void cvt8(const float* __restrict__ src, unsigned short* __restrict__ dst, int n) {
  int i = (blockIdx.x * 256 + threadIdx.x) * 8;
  if (i >= n) return;
  float4 a = *(const float4*)(src + i);
  float4 b = *(const float4*)(src + i + 4);
  union { unsigned short us[8]; uint4 u; } t;
  t.us[0] = f2bf(a.x); t.us[1] = f2bf(a.y); t.us[2] = f2bf(a.z); t.us[3] = f2bf(a.w);
  t.us[4] = f2bf(b.x); t.us[5] = f2bf(b.y); t.us[6] = f2bf(b.z); t.us[7] = f2bf(b.w);
  *(uint4*)(dst + i) = t.u;
}

// ---------------- generic GEMM: C[m,n] = sum_k A[m,k]*B[n,k] + bias[n] ----------------
template<int OUTBF>
__global__ __launch_bounds__(256, 2) void gemm_bt(
    const unsigned short* __restrict__ A,
    const unsigned short* __restrict__ Bw,
    const float* __restrict__ bias,
    void* __restrict__ Cout,
    int Mdim, int Ndim, int Kdim)
{
  __shared__ __align__(16) short As[128 * 64];
  __shared__ __align__(16) short Bs[128 * 64];
  const int tid = threadIdx.x;
  const int wave = tid >> 6, lane = tid & 63;
  const int wm = (wave >> 1) * 64, wn = (wave & 1) * 64;
  const int lr = lane & 15, lg = lane >> 4;
  const unsigned short* Ab = A + (size_t)blockIdx.y * 128 * Kdim;
  const unsigned short* Bb = Bw + (size_t)blockIdx.x * 128 * Kdim;

  f4v z = {0.f, 0.f, 0.f, 0.f};
  f4v acc[4][4];
  for (int mi = 0; mi < 4; mi++) for (int ni = 0; ni < 4; ni++) acc[mi][ni] = z;

  for (int k0 = 0; k0 < Kdim; k0 += 64) {
    __syncthreads();
    for (int i = 0; i < 4; i++) {
      int c = tid + i * 256;
      int row = c >> 3, kc = (c & 7) << 3;
      load_lds16(Ab + (size_t)row * Kdim + k0 + kc, As + c * 8);
      load_lds16(Bb + (size_t)row * Kdim + k0 + kc, Bs + c * 8);
    }
    __syncthreads();
    for (int kk = 0; kk < 64; kk += 32) {
      s8v af[4], bf[4];
      for (int i = 0; i < 4; i++)
        af[i] = *(const s8v*)(As + (wm + i * 16 + lr) * 64 + kk + lg * 8);
      for (int i = 0; i < 4; i++)
        bf[i] = *(const s8v*)(Bs + (wn + i * 16 + lr) * 64 + kk + lg * 8);
      for (int mi = 0; mi < 4; mi++)
        for (int ni = 0; ni < 4; ni++)
          acc[mi][ni] = __builtin_amdgcn_mfma_f32_16x16x32_bf16(af[mi], bf[ni], acc[mi][ni], 0, 0, 0);
    }
  }
  for (int ni = 0; ni < 4; ni++) {
    int col = blockIdx.x * 128 + wn + ni * 16 + lr;
    float bv = bias[col];
    for (int mi = 0; mi < 4; mi++) {
      int row0 = blockIdx.y * 128 + wm + mi * 16 + lg * 4;
      for (int r = 0; r < 4; r++) {
        float val = acc[mi][ni][r] + bv;
        if (OUTBF)
          ((unsigned short*)Cout)[(size_t)(row0 + r) * Ndim + col] = f2bf(val);
        else
          ((float*)Cout)[(size_t)(row0 + r) * Ndim + col] = val;
      }
    }
  }
}

// ---------------- fused QKV projection GEMM ----------------
// grid (24, 64): blockIdx.x>>3 selects segment (0=Q,1=K,2=V); &7 is N-tile.
__global__ __launch_bounds__(256, 2) void gemm_qkv(
    const unsigned short* __restrict__ qA, const unsigned short* __restrict__ kA,
    const unsigned short* __restrict__ vA,
    const unsigned short* __restrict__ wq, const unsigned short* __restrict__ wk,
    const unsigned short* __restrict__ wv,
    const float* __restrict__ bq, const float* __restrict__ bk, const float* __restrict__ bv,
    unsigned short* __restrict__ Qp, unsigned short* __restrict__ Kp,
    unsigned short* __restrict__ Vp)
{
  __shared__ __align__(16) short As[128 * 64];
  __shared__ __align__(16) short Bs[128 * 64];
  const int seg = blockIdx.x >> 3;
  const int nx = blockIdx.x & 7;
  const unsigned short* A  = seg == 0 ? qA : (seg == 1 ? kA : vA);
  const unsigned short* Bw = seg == 0 ? wq : (seg == 1 ? wk : wv);
  const float* bias        = seg == 0 ? bq : (seg == 1 ? bk : bv);
  unsigned short* Cout     = seg == 0 ? Qp : (seg == 1 ? Kp : Vp);

  const int tid = threadIdx.x;
  const int wave = tid >> 6, lane = tid & 63;
  const int wm = (wave >> 1) * 64, wn = (wave & 1) * 64;
  const int lr = lane & 15, lg = lane >> 4;
  const unsigned short* Ab = A + (size_t)blockIdx.y * 128 * DD;
  const unsigned short* Bb = Bw + (size_t)nx * 128 * DD;

  f4v z = {0.f, 0.f, 0.f, 0.f};
  f4v acc[4][4];
  for (int mi = 0; mi < 4; mi++) for (int ni = 0; ni < 4; ni++) acc[mi][ni] = z;

  for (int k0 = 0; k0 < DD; k0 += 64) {
    __syncthreads();
    for (int i = 0; i < 4; i++) {
      int c = tid + i * 256;
      int row = c >> 3, kc = (c & 7) << 3;
      load_lds16(Ab + (size_t)row * DD + k0 + kc, As + c * 8);
      load_lds16(Bb + (size_t)row * DD + k0 + kc, Bs + c * 8);
    }
    __syncthreads();
    for (int kk = 0; kk < 64; kk += 32) {
      s8v af[4], bf[4];
      for (int i = 0; i < 4; i++)
        af[i] = *(const s8v*)(As + (wm + i * 16 + lr) * 64 + kk + lg * 8);
      for (int i = 0; i < 4; i++)
        bf[i] = *(const s8v*)(Bs + (wn + i * 16 + lr) * 64 + kk + lg * 8);
      for (int mi = 0; mi < 4; mi++)
        for (int ni = 0; ni < 4; ni++)
          acc[mi][ni] = __builtin_amdgcn_mfma_f32_16x16x32_bf16(af[mi], bf[ni], acc[mi][ni], 0, 0, 0);
    }
  }
  for (int ni = 0; ni < 4; ni++) {
    int col = nx * 128 + wn + ni * 16 + lr;
    float bv = bias[col];
    for (int mi = 0; mi < 4; mi++) {
      int row0 = blockIdx.y * 128 + wm + mi * 16 + lg * 4;
      for (int r = 0; r < 4; r++)
        Cout[(size_t)(row0 + r) * DD + col] = f2bf(acc[mi][ni][r] + bv);
    }
  }
}

// ---------------- causal flash attention (paired Q-tiles) ----------------
// Each block handles Q-tiles xA=blockIdx.x and xB=NT-1-xA, sharing K/V staging.
// K/V staged 128 k-rows per barrier round. Per-lane distributed lsum.
__device__ __forceinline__ void attn_step(
    const s8v (&qf)[2][2], f4v (&o)[2][4], float (&m2)[2][4], float (&ls)[2][4],
    int qbase, int colbase, const short* __restrict__ KsSub,
    const short* __restrict__ Vt, int vsub, short* __restrict__ Pw,
    int lr, int lg, float csc)
{
  f4v zv = {0.f, 0.f, 0.f, 0.f};
  f4v s[2][4];
  for (int mi = 0; mi < 2; mi++) for (int ni = 0; ni < 4; ni++) s[mi][ni] = zv;
  for (int ks = 0; ks < 2; ks++) {
    s8v kf[4];
    for (int ni = 0; ni < 4; ni++)
      kf[ni] = *(const s8v*)(KsSub + (ni * 16 + lr) * 64 + ks * 32 + lg * 8);
    for (int mi = 0; mi < 2; mi++)
      for (int ni = 0; ni < 4; ni++)
        s[mi][ni] = __builtin_amdgcn_mfma_f32_16x16x32_bf16(qf[mi][ks], kf[ni], s[mi][ni], 0, 0, 0);
  }
  const bool diag = (colbase + 63 > qbase);
  for (int mi = 0; mi < 2; mi++)
    for (int ni = 0; ni < 4; ni++)
      for (int r = 0; r < 4; r++) {
        float t = s[mi][ni][r] * csc;
        if (diag) {
          int row = qbase + mi * 16 + lg * 4 + r;
          int col = colbase + ni * 16 + lr;
          if (col > row) t = -1e9f;
        }
        s[mi][ni][r] = t;
      }
  for (int mi = 0; mi < 2; mi++)
    for (int r = 0; r < 4; r++) {
      float mx = fmaxf(fmaxf(s[mi][0][r], s[mi][1][r]), fmaxf(s[mi][2][r], s[mi][3][r]));
      for (int d2 = 1; d2 < 16; d2 <<= 1) mx = fmaxf(mx, __shfl_xor(mx, d2));
      float mn = fmaxf(m2[mi][r], mx);
      float al = __builtin_amdgcn_exp2f(m2[mi][r] - mn);
      float ps = 0.f;
      for (int ni = 0; ni < 4; ni++) {
        float pp = __builtin_amdgcn_exp2f(s[mi][ni][r] - mn);
        s[mi][ni][r] = pp;
        ps += pp;
      }
      ls[mi][r] = ls[mi][r] * al + ps;   // per-lane partial; reduced in epilogue
      m2[mi][r] = mn;
      for (int ni = 0; ni < 4; ni++) o[mi][ni][r] *= al;
    }
  for (int mi = 0; mi < 2; mi++)
    for (int ni = 0; ni < 4; ni++)
      for (int r = 0; r < 4; r++)
        Pw[(mi * 16 + lg * 4 + r) * 72 + ni * 16 + lr] = (short)f2bf(s[mi][ni][r]);
  for (int kc2 = 0; kc2 < 2; kc2++) {
    s8v pf[2], vf[4];
    for (int mi = 0; mi < 2; mi++)
      pf[mi] = *(const s8v*)(Pw + (mi * 16 + lr) * 72 + kc2 * 32 + lg * 8);
    for (int ni = 0; ni < 4; ni++)
      vf[ni] = *(const s8v*)(Vt + (ni * 16 + lr) * 136 + vsub + kc2 * 32 + lg * 8);
    for (int mi = 0; mi < 2; mi++)
      for (int ni = 0; ni < 4; ni++)
        o[mi][ni] = __builtin_amdgcn_mfma_f32_16x16x32_bf16(pf[mi], vf[ni], o[mi][ni], 0, 0, 0);
  }
}

__global__ __launch_bounds__(256, 2) void fattn(
    const unsigned short* __restrict__ Qp,
    const unsigned short* __restrict__ Kp,
    const unsigned short* __restrict__ Vp,
    unsigned short* __restrict__ Op)
{
  __shared__ __align__(16) short Ks[128 * 64];     // K pair-tile [kr][d]
  __shared__ __align__(16) short Vt[64 * 136];     // V^T pair-tile [d][kr], padded
  __shared__ __align__(16) short Ps[4 * 32 * 72];  // per-wave P, padded
  const int tid = threadIdx.x;
  const int wave = tid >> 6, lane = tid & 63;
  const int lr = lane & 15, lg = lane >> 4;
  const int b = blockIdx.y >> 4, h = blockIdx.y & 15;
  const int xA = blockIdx.x, xB = NT - 1 - xA;
  const int qbA = xA * 128 + wave * 32;
  const int qbB = xB * 128 + wave * 32;
  const unsigned short* Qrow = Qp + ((size_t)b * SEQ) * DD + h * DHEAD;
  const unsigned short* Krow = Kp + ((size_t)b * SEQ) * DD + h * DHEAD;
  const unsigned short* Vrow = Vp + ((size_t)b * SEQ) * DD + h * DHEAD;
  short* Pw = Ps + wave * (32 * 72);

  s8v qfA[2][2], qfB[2][2];
  for (int mi = 0; mi < 2; mi++)
    for (int ks = 0; ks < 2; ks++) {
      qfA[mi][ks] = *(const s8v*)(Qrow + (size_t)(qbA + mi * 16 + lr) * DD + ks * 32 + lg * 8);
      qfB[mi][ks] = *(const s8v*)(Qrow + (size_t)(qbB + mi * 16 + lr) * DD + ks * 32 + lg * 8);
    }

  f4v zv = {0.f, 0.f, 0.f, 0.f};
  f4v oA[2][4], oB[2][4];
  float mA[2][4], lA[2][4], mB[2][4], lB[2][4];
  for (int mi = 0; mi < 2; mi++)
    for (int r = 0; r < 4; r++) {
      mA[mi][r] = -1e30f; lA[mi][r] = 0.f;
      mB[mi][r] = -1e30f; lB[mi][r] = 0.f;
    }
  for (int mi = 0; mi < 2; mi++)
    for (int ni = 0; ni < 4; ni++) { oA[mi][ni] = zv; oB[mi][ni] = zv; }

  const float csc = 0.125f * 1.44269504089f;
  const int npair = xB + 1;   // 128-row k-pairs; covers both tiles' causal ranges

  for (int p = 0; p < npair; p++) {
    __syncthreads();
    // stage K pair-tile (128 x 64) async
    for (int i = 0; i < 4; i++) {
      int c = tid + i * 256;
      int row = c >> 3, kc = (c & 7) << 3;
      load_lds16(Krow + (size_t)(p * 128 + row) * DD + kc, Ks + c * 8);
    }
    // stage V^T (transpose in flight), stride 136
    for (int i = 0; i < 2; i++) {
      int c = (tid >> 2) + i * 64;
      int dbase = (tid & 3) << 4;
      const unsigned short* vsrc = Vrow + (size_t)(p * 128 + c) * DD + dbase;
      for (int half = 0; half < 2; half++) {
        s8v vv = *(const s8v*)(vsrc + half * 8);
        for (int j = 0; j < 8; j++)
          Vt[(dbase + half * 8 + j) * 136 + c] = vv[j];
      }
    }
    __syncthreads();
    for (int sub = 0; sub < 2; sub++) {
      int colbase = (2 * p + sub) * 64;
      const short* KsSub = Ks + sub * 64 * 64;
      int vsub = sub * 64;
      if (colbase <= qbB + 31)
        attn_step(qfB, oB, mB, lB, qbB, colbase, KsSub, Vt, vsub, Pw, lr, lg, csc);
      if (colbase <= qbA + 31)
        attn_step(qfA, oA, mA, lA, qbA, colbase, KsSub, Vt, vsub, Pw, lr, lg, csc);
    }
  }

  // epilogue: reduce distributed lsum across the 16-lane row groups, store
  unsigned short* Orow = Op + ((size_t)b * SEQ) * DD + h * DHEAD;
  for (int mi = 0; mi < 2; mi++)
    for (int r = 0; r < 4; r++) {
      float sA = lA[mi][r], sB = lB[mi][r];
      for (int d2 = 1; d2 < 16; d2 <<= 1) {
        sA += __shfl_xor(sA, d2);
        sB += __shfl_xor(sB, d2);
      }
      float invA = 1.f / sA, invB = 1.f / sB;
      size_t rowA = (size_t)qbA + mi * 16 + lg * 4 + r;
      size_t rowB = (size_t)qbB + mi * 16 + lg * 4 + r;
      for (int ni = 0; ni < 4; ni++) {
        Orow[rowA * DD + ni * 16 + lr] = f2bf(oA[mi][ni][r] * invA);
        Orow[rowB * DD + ni * 16 + lr] = f2bf(oB[mi][ni][r] * invB);
      }
    }
}

// ---------------- launcher ----------------
extern "C" void kernel_launch(void* const* d_in, const int* in_sizes, int n_in,
                              void* d_out, int out_size, void* d_ws, size_t ws_size,
                              hipStream_t stream) {
  const float* q    = (const float*)d_in[0];
  const float* k    = (const float*)d_in[1];
  const float* v    = (const float*)d_in[2];
  const float* wq_w = (const float*)d_in[3];
  const float* wq_b = (const float*)d_in[4];
  const float* wk_w = (const float*)d_in[5];
  const float* wk_b = (const float*)d_in[6];
  const float* wv_w = (const float*)d_in[7];
  const float* wv_b = (const float*)d_in[8];
  const float* wo_w = (const float*)d_in[9];
  const float* wo_b = (const float*)d_in[10];

  const size_t BIG = (size_t)MR * DD;
  const size_t WSZ = (size_t)DD * DD;
  unsigned short* p = (unsigned short*)d_ws;
  unsigned short* qb  = p; p += BIG;
  unsigned short* kb  = p; p += BIG;
  unsigned short* vb  = p; p += BIG;
  unsigned short* wqb = p; p += WSZ;
  unsigned short* wkb = p; p += WSZ;
  unsigned short* wvb = p; p += WSZ;
  unsigned short* wob = p; p += WSZ;
  unsigned short* Qp  = p; p += BIG;
  unsigned short* Kp  = p; p += BIG;
  unsigned short* Vp  = p; p += BIG;
  unsigned short* AO  = p; p += BIG;

  cvt8<<<dim3(BIG / 8 / 256), dim3(256), 0, stream>>>(q, qb, (int)BIG);
  cvt8<<<dim3(BIG / 8 / 256), dim3(256), 0, stream>>>(k, kb, (int)BIG);
  cvt8<<<dim3(BIG / 8 / 256), dim3(256), 0, stream>>>(v, vb, (int)BIG);
  cvt8<<<dim3(WSZ / 8 / 256), dim3(256), 0, stream>>>(wq_w, wqb, (int)WSZ);
  cvt8<<<dim3(WSZ / 8 / 256), dim3(256), 0, stream>>>(wk_w, wkb, (int)WSZ);
  cvt8<<<dim3(WSZ / 8 / 256), dim3(256), 0, stream>>>(wv_w, wvb, (int)WSZ);
  cvt8<<<dim3(WSZ / 8 / 256), dim3(256), 0, stream>>>(wo_w, wob, (int)WSZ);

  // fused QKV projections -> bf16 [B,L,H,DK]
  gemm_qkv<<<dim3(24, MR / 128), dim3(256), 0, stream>>>(
      qb, kb, vb, wqb, wkb, wvb, wq_b, wk_b, wv_b, Qp, Kp, Vp);

  // paired-tile causal flash attention
  fattn<<<dim3(NT / 2, NB * NH), dim3(256), 0, stream>>>(Qp, Kp, Vp, AO);

  // output projection -> fp32 d_out
  gemm_bt<0><<<dim3(DD / 128, MR / 128), dim3(256), 0, stream>>>(
      AO, wob, wo_b, (float*)d_out, MR, DD, DD);

  (void)in_sizes; (void)n_in; (void)out_size; (void)ws_size;
}

// Round 3
// 331.714 us; speedup vs baseline: 1.6687x; 1.2354x over previous
//
#include <hip/hip_runtime.h>
#include <stdint.h>

#define DD 1024      // model dim
#define NH 16        // heads
#define DHEAD 64     // head dim
#define NB 4         // batch
#define SEQ 2048     // seq len
#define MR (NB*SEQ)  // 8192 rows
#define NT (SEQ/128) // 16 Q-tiles of 128 rows

typedef __attribute__((ext_vector_type(8))) short s8v;
typedef __attribute__((ext_vector_type(4))) float f4v;

__device__ __forceinline__ unsigned short f2bf(float f) {
  union { float f; uint32_t u; } c; c.f = f;
  uint32_t u = c.u;
  u += 0x7fffu + ((u >> 16) & 1u);   // RNE
  return (unsigned short)(u >> 16);
}
__device__ __forceinline__ unsigned short f2bf_trunc(float f) {
  union { float f; uint32_t u; } c; c.f = f;
  return (unsigned short)(c.u >> 16);
}

__device__ __forceinline__ void load_lds16(const void* g, void* lds) {
  __builtin_amdgcn_global_load_lds(
      (__attribute__((address_space(1))) void*)(uintptr_t)g,
      (__attribute__((address_space(3))) void*)(uint32_t)(uintptr_t)lds,
      16, 0, 0);
}

// ---------------- fp32 -> bf16 converts (merged launches) ----------------
__global__ void cvt3(const float* __restrict__ s0, const float* __restrict__ s1,
                     const float* __restrict__ s2,
                     unsigned short* __restrict__ d0, unsigned short* __restrict__ d1,
                     unsigned short* __restrict__ d2) {
  const float* src = blockIdx.y == 0 ? s0 : (blockIdx.y == 1 ? s1 : s2);
  unsigned short* dst = blockIdx.y == 0 ? d0 : (blockIdx.y == 1 ? d1 : d2);
  int i = (blockIdx.x * 256 + threadIdx.x) * 8;
  float4 a = *(const float4*)(src + i);
  float4 b = *(const float4*)(src + i + 4);
  union { unsigned short us[8]; uint4 u; } t;
  t.us[0] = f2bf(a.x); t.us[1] = f2bf(a.y); t.us[2] = f2bf(a.z); t.us[3] = f2bf(a.w);
  t.us[4] = f2bf(b.x); t.us[5] = f2bf(b.y); t.us[6] = f2bf(b.z); t.us[7] = f2bf(b.w);
  *(uint4*)(dst + i) = t.u;
}
__global__ void cvt4(const float* __restrict__ s0, const float* __restrict__ s1,
                     const float* __restrict__ s2, const float* __restrict__ s3,
                     unsigned short* __restrict__ d0, unsigned short* __restrict__ d1,
                     unsigned short* __restrict__ d2, unsigned short* __restrict__ d3) {
  const float* src = blockIdx.y == 0 ? s0 : (blockIdx.y == 1 ? s1 : (blockIdx.y == 2 ? s2 : s3));
  unsigned short* dst = blockIdx.y == 0 ? d0 : (blockIdx.y == 1 ? d1 : (blockIdx.y == 2 ? d2 : d3));
  int i = (blockIdx.x * 256 + threadIdx.x) * 8;
  float4 a = *(const float4*)(src + i);
  float4 b = *(const float4*)(src + i + 4);
  union { unsigned short us[8]; uint4 u; } t;
  t.us[0] = f2bf(a.x); t.us[1] = f2bf(a.y); t.us[2] = f2bf(a.z); t.us[3] = f2bf(a.w);
  t.us[4] = f2bf(b.x); t.us[5] = f2bf(b.y); t.us[6] = f2bf(b.z); t.us[7] = f2bf(b.w);
  *(uint4*)(dst + i) = t.u;
}

// ---------------- generic GEMM: C[m,n] = sum_k A[m,k]*B[n,k] + bias[n] ----------------
template<int OUTBF>
__global__ __launch_bounds__(256, 2) void gemm_bt(
    const unsigned short* __restrict__ A,
    const unsigned short* __restrict__ Bw,
    const float* __restrict__ bias,
    void* __restrict__ Cout,
    int Mdim, int Ndim, int Kdim)
{
  __shared__ __align__(16) short As[128 * 64];
  __shared__ __align__(16) short Bs[128 * 64];
  const int tid = threadIdx.x;
  const int wave = tid >> 6, lane = tid & 63;
  const int wm = (wave >> 1) * 64, wn = (wave & 1) * 64;
  const int lr = lane & 15, lg = lane >> 4;
  const unsigned short* Ab = A + (size_t)blockIdx.y * 128 * Kdim;
  const unsigned short* Bb = Bw + (size_t)blockIdx.x * 128 * Kdim;

  f4v z = {0.f, 0.f, 0.f, 0.f};
  f4v acc[4][4];
  for (int mi = 0; mi < 4; mi++) for (int ni = 0; ni < 4; ni++) acc[mi][ni] = z;

  for (int k0 = 0; k0 < Kdim; k0 += 64) {
    __syncthreads();
    for (int i = 0; i < 4; i++) {
      int c = tid + i * 256;
      int row = c >> 3, kc = (c & 7) << 3;
      load_lds16(Ab + (size_t)row * Kdim + k0 + kc, As + c * 8);
      load_lds16(Bb + (size_t)row * Kdim + k0 + kc, Bs + c * 8);
    }
    __syncthreads();
    for (int kk = 0; kk < 64; kk += 32) {
      s8v af[4], bf[4];
      for (int i = 0; i < 4; i++)
        af[i] = *(const s8v*)(As + (wm + i * 16 + lr) * 64 + kk + lg * 8);
      for (int i = 0; i < 4; i++)
        bf[i] = *(const s8v*)(Bs + (wn + i * 16 + lr) * 64 + kk + lg * 8);
      for (int mi = 0; mi < 4; mi++)
        for (int ni = 0; ni < 4; ni++)
          acc[mi][ni] = __builtin_amdgcn_mfma_f32_16x16x32_bf16(af[mi], bf[ni], acc[mi][ni], 0, 0, 0);
    }
  }
  for (int ni = 0; ni < 4; ni++) {
    int col = blockIdx.x * 128 + wn + ni * 16 + lr;
    float bv = bias[col];
    for (int mi = 0; mi < 4; mi++) {
      int row0 = blockIdx.y * 128 + wm + mi * 16 + lg * 4;
      for (int r = 0; r < 4; r++) {
        float val = acc[mi][ni][r] + bv;
        if (OUTBF)
          ((unsigned short*)Cout)[(size_t)(row0 + r) * Ndim + col] = f2bf(val);
        else
          ((float*)Cout)[(size_t)(row0 + r) * Ndim + col] = val;
      }
    }
  }
}

// ---------------- fused QKV projection GEMM ----------------
// grid (24, 64): seg = blockIdx.x>>3 (0=Q,1=K,2=V); V written TRANSPOSED:
// VpT[(b*NH+h)*64 + d][l]  (per-(b,h) [DK][SEQ]).
__global__ __launch_bounds__(256, 2) void gemm_qkv(
    const unsigned short* __restrict__ qA, const unsigned short* __restrict__ kA,
    const unsigned short* __restrict__ vA,
    const unsigned short* __restrict__ wq, const unsigned short* __restrict__ wk,
    const unsigned short* __restrict__ wv,
    const float* __restrict__ bq, const float* __restrict__ bk, const float* __restrict__ bv,
    unsigned short* __restrict__ Qp, unsigned short* __restrict__ Kp,
    unsigned short* __restrict__ VpT)
{
  __shared__ __align__(16) short As[128 * 64];
  __shared__ __align__(16) short Bs[128 * 64];
  const int seg = blockIdx.x >> 3;
  const int nx = blockIdx.x & 7;
  const unsigned short* A  = seg == 0 ? qA : (seg == 1 ? kA : vA);
  const unsigned short* Bw = seg == 0 ? wq : (seg == 1 ? wk : wv);
  const float* bias        = seg == 0 ? bq : (seg == 1 ? bk : bv);

  const int tid = threadIdx.x;
  const int wave = tid >> 6, lane = tid & 63;
  const int wm = (wave >> 1) * 64, wn = (wave & 1) * 64;
  const int lr = lane & 15, lg = lane >> 4;
  const unsigned short* Ab = A + (size_t)blockIdx.y * 128 * DD;
  const unsigned short* Bb = Bw + (size_t)nx * 128 * DD;

  f4v z = {0.f, 0.f, 0.f, 0.f};
  f4v acc[4][4];
  for (int mi = 0; mi < 4; mi++) for (int ni = 0; ni < 4; ni++) acc[mi][ni] = z;

  for (int k0 = 0; k0 < DD; k0 += 64) {
    __syncthreads();
    for (int i = 0; i < 4; i++) {
      int c = tid + i * 256;
      int row = c >> 3, kc = (c & 7) << 3;
      load_lds16(Ab + (size_t)row * DD + k0 + kc, As + c * 8);
      load_lds16(Bb + (size_t)row * DD + k0 + kc, Bs + c * 8);
    }
    __syncthreads();
    for (int kk = 0; kk < 64; kk += 32) {
      s8v af[4], bf[4];
      for (int i = 0; i < 4; i++)
        af[i] = *(const s8v*)(As + (wm + i * 16 + lr) * 64 + kk + lg * 8);
      for (int i = 0; i < 4; i++)
        bf[i] = *(const s8v*)(Bs + (wn + i * 16 + lr) * 64 + kk + lg * 8);
      for (int mi = 0; mi < 4; mi++)
        for (int ni = 0; ni < 4; ni++)
          acc[mi][ni] = __builtin_amdgcn_mfma_f32_16x16x32_bf16(af[mi], bf[ni], acc[mi][ni], 0, 0, 0);
    }
  }
  if (seg < 2) {
    unsigned short* Cout = seg == 0 ? Qp : Kp;
    for (int ni = 0; ni < 4; ni++) {
      int col = nx * 128 + wn + ni * 16 + lr;
      float bv = bias[col];
      for (int mi = 0; mi < 4; mi++) {
        int row0 = blockIdx.y * 128 + wm + mi * 16 + lg * 4;
        for (int r = 0; r < 4; r++)
          Cout[(size_t)(row0 + r) * DD + col] = f2bf(acc[mi][ni][r] + bv);
      }
    }
  } else {
    // V: transposed, 4 seq-consecutive rows packed into one 8B store
    for (int ni = 0; ni < 4; ni++) {
      int col = nx * 128 + wn + ni * 16 + lr;
      float bv = bias[col];
      int hh = col >> 6, dd = col & 63;
      for (int mi = 0; mi < 4; mi++) {
        int row0 = blockIdx.y * 128 + wm + mi * 16 + lg * 4;
        int bb = row0 >> 11, ll = row0 & 2047;
        uint64_t w = 0;
        for (int r = 0; r < 4; r++)
          w |= (uint64_t)f2bf(acc[ni & 3][ni][r] * 0.f + acc[mi][ni][r] + bv) << (16 * r);
        *(uint64_t*)(VpT + ((size_t)(bb * NH + hh) * 64 + dd) * SEQ + ll) = w;
      }
    }
  }
}

// ---------------- causal flash attention (paired Q-tiles, static max) ----------------
#define KS_STRIDE 72
#define VT_STRIDE 136
#define PS_STRIDE 72

__device__ __forceinline__ void attn_step(
    const s8v (&qf)[2][2], const s8v (&kf)[2][4],
    f4v (&o)[2][4], float (&ls)[2][4],
    int qbase, int colbase,
    const short* __restrict__ Vt, int vsub, short* __restrict__ Pw,
    int lr, int lg)
{
  const float csc = 0.125f * 1.44269504089f;
  const float FM = 14.0f;
  f4v zv = {0.f, 0.f, 0.f, 0.f};
  f4v s[2][4];
  for (int mi = 0; mi < 2; mi++) for (int ni = 0; ni < 4; ni++) s[mi][ni] = zv;
  for (int ks = 0; ks < 2; ks++)
    for (int mi = 0; mi < 2; mi++)
      for (int ni = 0; ni < 4; ni++)
        s[mi][ni] = __builtin_amdgcn_mfma_f32_16x16x32_bf16(qf[mi][ks], kf[ks][ni], s[mi][ni], 0, 0, 0);
  const bool diag = (colbase + 63 > qbase);
  for (int mi = 0; mi < 2; mi++)
    for (int ni = 0; ni < 4; ni++)
      for (int r = 0; r < 4; r++) {
        float e = __builtin_amdgcn_exp2f(fmaf(s[mi][ni][r], csc, -FM));
        if (diag) {
          int row = qbase + mi * 16 + lg * 4 + r;
          int col = colbase + ni * 16 + lr;
          e = (col > row) ? 0.f : e;
        }
        ls[mi][r] += e;
        Pw[(mi * 16 + lg * 4 + r) * PS_STRIDE + ni * 16 + lr] = (short)f2bf_trunc(e);
      }
  for (int kc2 = 0; kc2 < 2; kc2++) {
    s8v pf[2], vf[4];
    for (int mi = 0; mi < 2; mi++)
      pf[mi] = *(const s8v*)(Pw + (mi * 16 + lr) * PS_STRIDE + kc2 * 32 + lg * 8);
    for (int ni = 0; ni < 4; ni++)
      vf[ni] = *(const s8v*)(Vt + (ni * 16 + lr) * VT_STRIDE + vsub + kc2 * 32 + lg * 8);
    for (int mi = 0; mi < 2; mi++)
      for (int ni = 0; ni < 4; ni++)
        o[mi][ni] = __builtin_amdgcn_mfma_f32_16x16x32_bf16(pf[mi], vf[ni], o[mi][ni], 0, 0, 0);
  }
}

__global__ __launch_bounds__(256, 2) void fattn(
    const unsigned short* __restrict__ Qp,
    const unsigned short* __restrict__ Kp,
    const unsigned short* __restrict__ VpT,
    unsigned short* __restrict__ Op)
{
  __shared__ __align__(16) short Ks[128 * KS_STRIDE];
  __shared__ __align__(16) short Vt[64 * VT_STRIDE];
  __shared__ __align__(16) short Ps[4 * 32 * PS_STRIDE];
  const int tid = threadIdx.x;
  const int wave = tid >> 6, lane = tid & 63;
  const int lr = lane & 15, lg = lane >> 4;
  const int bh = blockIdx.y;
  const int b = bh >> 4, h = bh & 15;
  const int xA = blockIdx.x, xB = NT - 1 - xA;
  const int qbA = xA * 128 + wave * 32;
  const int qbB = xB * 128 + wave * 32;
  const unsigned short* Qrow = Qp + ((size_t)b * SEQ) * DD + h * DHEAD;
  const unsigned short* Krow = Kp + ((size_t)b * SEQ) * DD + h * DHEAD;
  const unsigned short* VT   = VpT + (size_t)bh * 64 * SEQ;
  short* Pw = Ps + wave * (32 * PS_STRIDE);

  s8v qfA[2][2], qfB[2][2];
  for (int mi = 0; mi < 2; mi++)
    for (int ks = 0; ks < 2; ks++) {
      qfA[mi][ks] = *(const s8v*)(Qrow + (size_t)(qbA + mi * 16 + lr) * DD + ks * 32 + lg * 8);
      qfB[mi][ks] = *(const s8v*)(Qrow + (size_t)(qbB + mi * 16 + lr) * DD + ks * 32 + lg * 8);
    }

  f4v zv = {0.f, 0.f, 0.f, 0.f};
  f4v oA[2][4], oB[2][4];
  float lA[2][4], lB[2][4];
  for (int mi = 0; mi < 2; mi++)
    for (int r = 0; r < 4; r++) { lA[mi][r] = 0.f; lB[mi][r] = 0.f; }
  for (int mi = 0; mi < 2; mi++)
    for (int ni = 0; ni < 4; ni++) { oA[mi][ni] = zv; oB[mi][ni] = zv; }

  const int npair = xB + 1;

  for (int p = 0; p < npair; p++) {
    // load staging data to registers (16B vector loads)
    s8v kreg[4], vreg[4];
    int krow[4], kkc[4], vd[4], vkc[4];
    for (int i = 0; i < 4; i++) {
      int c = tid + i * 256;
      krow[i] = c >> 3; kkc[i] = (c & 7) << 3;
      kreg[i] = *(const s8v*)(Krow + (size_t)(p * 128 + krow[i]) * DD + kkc[i]);
      vd[i] = c >> 4; vkc[i] = (c & 15) << 3;
      vreg[i] = *(const s8v*)(VT + (size_t)vd[i] * SEQ + p * 128 + vkc[i]);
    }
    __syncthreads();   // prior round's LDS reads done
    for (int i = 0; i < 4; i++) {
      *(s8v*)(Ks + krow[i] * KS_STRIDE + kkc[i]) = kreg[i];
      *(s8v*)(Vt + vd[i] * VT_STRIDE + vkc[i]) = vreg[i];
    }
    __syncthreads();
    for (int sub = 0; sub < 2; sub++) {
      int colbase = (2 * p + sub) * 64;
      bool actB = colbase <= qbB + 31;
      bool actA = colbase <= qbA + 31;
      if (actB || actA) {
        const short* KsSub = Ks + sub * 64 * KS_STRIDE;
        s8v kf[2][4];
        for (int ks = 0; ks < 2; ks++)
          for (int ni = 0; ni < 4; ni++)
            kf[ks][ni] = *(const s8v*)(KsSub + (ni * 16 + lr) * KS_STRIDE + ks * 32 + lg * 8);
        int vsub = sub * 64;
        if (actB) attn_step(qfB, kf, oB, lB, qbB, colbase, Vt, vsub, Pw, lr, lg);
        if (actA) attn_step(qfA, kf, oA, lA, qbA, colbase, Vt, vsub, Pw, lr, lg);
      }
    }
  }

  // epilogue: reduce distributed lsum across 16-lane row groups, store
  unsigned short* Orow = Op + ((size_t)b * SEQ) * DD + h * DHEAD;
  for (int mi = 0; mi < 2; mi++)
    for (int r = 0; r < 4; r++) {
      float sA = lA[mi][r], sB = lB[mi][r];
      for (int d2 = 1; d2 < 16; d2 <<= 1) {
        sA += __shfl_xor(sA, d2);
        sB += __shfl_xor(sB, d2);
      }
      float invA = 1.f / sA, invB = 1.f / sB;
      size_t rowA = (size_t)qbA + mi * 16 + lg * 4 + r;
      size_t rowB = (size_t)qbB + mi * 16 + lg * 4 + r;
      for (int ni = 0; ni < 4; ni++) {
        Orow[rowA * DD + ni * 16 + lr] = f2bf(oA[mi][ni][r] * invA);
        Orow[rowB * DD + ni * 16 + lr] = f2bf(oB[mi][ni][r] * invB);
      }
    }
}

// ---------------- launcher ----------------
extern "C" void kernel_launch(void* const* d_in, const int* in_sizes, int n_in,
                              void* d_out, int out_size, void* d_ws, size_t ws_size,
                              hipStream_t stream) {
  const float* q    = (const float*)d_in[0];
  const float* k    = (const float*)d_in[1];
  const float* v    = (const float*)d_in[2];
  const float* wq_w = (const float*)d_in[3];
  const float* wq_b = (const float*)d_in[4];
  const float* wk_w = (const float*)d_in[5];
  const float* wk_b = (const float*)d_in[6];
  const float* wv_w = (const float*)d_in[7];
  const float* wv_b = (const float*)d_in[8];
  const float* wo_w = (const float*)d_in[9];
  const float* wo_b = (const float*)d_in[10];

  const size_t BIG = (size_t)MR * DD;
  const size_t WSZ = (size_t)DD * DD;
  unsigned short* p = (unsigned short*)d_ws;
  unsigned short* qb  = p; p += BIG;
  unsigned short* kb  = p; p += BIG;
  unsigned short* vb  = p; p += BIG;
  unsigned short* wqb = p; p += WSZ;
  unsigned short* wkb = p; p += WSZ;
  unsigned short* wvb = p; p += WSZ;
  unsigned short* wob = p; p += WSZ;
  unsigned short* Qp  = p; p += BIG;
  unsigned short* Kp  = p; p += BIG;
  unsigned short* VpT = p; p += BIG;   // [bh][64][SEQ]
  unsigned short* AO  = p; p += BIG;

  cvt3<<<dim3(BIG / 8 / 256, 3), dim3(256), 0, stream>>>(q, k, v, qb, kb, vb);
  cvt4<<<dim3(WSZ / 8 / 256, 4), dim3(256), 0, stream>>>(
      wq_w, wk_w, wv_w, wo_w, wqb, wkb, wvb, wob);

  // fused QKV projections; V written transposed
  gemm_qkv<<<dim3(24, MR / 128), dim3(256), 0, stream>>>(
      qb, kb, vb, wqb, wkb, wvb, wq_b, wk_b, wv_b, Qp, Kp, VpT);

  // paired-tile causal flash attention (static max)
  fattn<<<dim3(NT / 2, NB * NH), dim3(256), 0, stream>>>(Qp, Kp, VpT, AO);

  // output projection -> fp32 d_out
  gemm_bt<0><<<dim3(DD / 128, MR / 128), dim3(256), 0, stream>>>(
      AO, wob, wo_b, (float*)d_out, MR, DD, DD);

  (void)in_sizes; (void)n_in; (void)out_size; (void)ws_size;
}

// Round 4
// 326.858 us; speedup vs baseline: 1.6935x; 1.0149x over previous
//
#include <hip/hip_runtime.h>
#include <stdint.h>

#define DD 1024      // model dim
#define NH 16        // heads
#define DHEAD 64     // head dim
#define NB 4         // batch
#define SEQ 2048     // seq len
#define MR (NB*SEQ)  // 8192 rows
#define NT (SEQ/128) // 16 Q-tiles of 128 rows

typedef __attribute__((ext_vector_type(8))) short s8v;
typedef __attribute__((ext_vector_type(4))) float f4v;

__device__ __forceinline__ unsigned short f2bf(float f) {
  union { float f; uint32_t u; } c; c.f = f;
  uint32_t u = c.u;
  u += 0x7fffu + ((u >> 16) & 1u);   // RNE
  return (unsigned short)(u >> 16);
}
__device__ __forceinline__ unsigned short f2bf_trunc(float f) {
  union { float f; uint32_t u; } c; c.f = f;
  return (unsigned short)(c.u >> 16);
}

__device__ __forceinline__ void load_lds16(const void* g, void* lds) {
  __builtin_amdgcn_global_load_lds(
      (__attribute__((address_space(1))) void*)(uintptr_t)g,
      (__attribute__((address_space(3))) void*)(uint32_t)(uintptr_t)lds,
      16, 0, 0);
}

// ---------------- fp32 -> bf16 convert, single kernel for all 7 arrays ------
// blocks 0..12287: q,k,v (4096 blocks each); 12288..14335: 4 weights (512 each)
__global__ void cvt_all(
    const float* __restrict__ q, const float* __restrict__ k, const float* __restrict__ v,
    const float* __restrict__ w0, const float* __restrict__ w1,
    const float* __restrict__ w2, const float* __restrict__ w3,
    unsigned short* __restrict__ qb, unsigned short* __restrict__ kb,
    unsigned short* __restrict__ vb,
    unsigned short* __restrict__ w0b, unsigned short* __restrict__ w1b,
    unsigned short* __restrict__ w2b, unsigned short* __restrict__ w3b)
{
  int blk = blockIdx.x;
  const float* src; unsigned short* dst; size_t off;
  if (blk < 12288) {
    int a = blk >> 12;
    src = a == 0 ? q : (a == 1 ? k : v);
    dst = a == 0 ? qb : (a == 1 ? kb : vb);
    off = (size_t)(blk & 4095) * 2048;
  } else {
    int wb = blk - 12288;
    int a = wb >> 9;
    src = a == 0 ? w0 : (a == 1 ? w1 : (a == 2 ? w2 : w3));
    dst = a == 0 ? w0b : (a == 1 ? w1b : (a == 2 ? w2b : w3b));
    off = (size_t)(wb & 511) * 2048;
  }
  size_t i = off + (size_t)threadIdx.x * 8;
  float4 a4 = *(const float4*)(src + i);
  float4 b4 = *(const float4*)(src + i + 4);
  union { unsigned short us[8]; uint4 u; } t;
  t.us[0] = f2bf(a4.x); t.us[1] = f2bf(a4.y); t.us[2] = f2bf(a4.z); t.us[3] = f2bf(a4.w);
  t.us[4] = f2bf(b4.x); t.us[5] = f2bf(b4.y); t.us[6] = f2bf(b4.z); t.us[7] = f2bf(b4.w);
  *(uint4*)(dst + i) = t.u;
}

// ---------------- output projection GEMM: 64x128 tiles, XCD-swizzled --------
// C[m,n] = sum_k A[m,k]*B[n,k] + bias[n], fp32 out. 1024 blocks.
__global__ __launch_bounds__(256, 2) void gemm_bt(
    const unsigned short* __restrict__ A,
    const unsigned short* __restrict__ Bw,
    const float* __restrict__ bias,
    float* __restrict__ Cout)
{
  __shared__ __align__(16) short As[64 * 64];
  __shared__ __align__(16) short Bs[128 * 64];
  // swizzle: XCD = linear%8 = my%8 -> co-readers of an A-tile share an XCD
  const int linear = blockIdx.y * 8 + blockIdx.x;
  const int nx = linear >> 7;        // 0..7 weight column tile
  const int my = linear & 127;       // 0..127 M tile (64 rows)
  const int tid = threadIdx.x;
  const int wave = tid >> 6, lane = tid & 63;
  const int wm = (wave >> 1) * 32, wn = (wave & 1) * 64;
  const int lr = lane & 15, lg = lane >> 4;
  const unsigned short* Ab = A + (size_t)my * 64 * DD;
  const unsigned short* Bb = Bw + (size_t)nx * 128 * DD;

  f4v z = {0.f, 0.f, 0.f, 0.f};
  f4v acc[2][4];
  for (int mi = 0; mi < 2; mi++) for (int ni = 0; ni < 4; ni++) acc[mi][ni] = z;

  for (int k0 = 0; k0 < DD; k0 += 64) {
    __syncthreads();
    for (int i = 0; i < 2; i++) {
      int c = tid + i * 256;
      int row = c >> 3, kc = (c & 7) << 3;
      load_lds16(Ab + (size_t)row * DD + k0 + kc, As + c * 8);
    }
    for (int i = 0; i < 4; i++) {
      int c = tid + i * 256;
      int row = c >> 3, kc = (c & 7) << 3;
      load_lds16(Bb + (size_t)row * DD + k0 + kc, Bs + c * 8);
    }
    __syncthreads();
    for (int kk = 0; kk < 64; kk += 32) {
      s8v af[2], bf[4];
      for (int i = 0; i < 2; i++)
        af[i] = *(const s8v*)(As + (wm + i * 16 + lr) * 64 + kk + lg * 8);
      for (int i = 0; i < 4; i++)
        bf[i] = *(const s8v*)(Bs + (wn + i * 16 + lr) * 64 + kk + lg * 8);
      for (int mi = 0; mi < 2; mi++)
        for (int ni = 0; ni < 4; ni++)
          acc[mi][ni] = __builtin_amdgcn_mfma_f32_16x16x32_bf16(af[mi], bf[ni], acc[mi][ni], 0, 0, 0);
    }
  }
  for (int ni = 0; ni < 4; ni++) {
    int col = nx * 128 + wn + ni * 16 + lr;
    float bv = bias[col];
    for (int mi = 0; mi < 2; mi++) {
      int row0 = my * 64 + wm + mi * 16 + lg * 4;
      for (int r = 0; r < 4; r++)
        Cout[(size_t)(row0 + r) * DD + col] = acc[mi][ni][r] + bv;
    }
  }
}

// ---------------- fused QKV projection GEMM, XCD-swizzled -------------------
// 1536 blocks; role remap so XCD = my%8: all (seg,nx) for a given M-row share
// an XCD -> A-tiles fetched once per XCD L2 instead of 8x.
__global__ __launch_bounds__(256, 2) void gemm_qkv(
    const unsigned short* __restrict__ qA, const unsigned short* __restrict__ kA,
    const unsigned short* __restrict__ vA,
    const unsigned short* __restrict__ wq, const unsigned short* __restrict__ wk,
    const unsigned short* __restrict__ wv,
    const float* __restrict__ bq, const float* __restrict__ bk, const float* __restrict__ bv,
    unsigned short* __restrict__ Qp, unsigned short* __restrict__ Kp,
    unsigned short* __restrict__ VpT)
{
  __shared__ __align__(16) short As[128 * 64];
  __shared__ __align__(16) short Bs[128 * 64];
  const int linear = blockIdx.y * 24 + blockIdx.x;
  const int nx  = linear / 192;        // 0..7
  const int rem = linear % 192;
  const int seg = rem >> 6;            // 0..2
  const int my  = rem & 63;            // 0..63
  const unsigned short* A  = seg == 0 ? qA : (seg == 1 ? kA : vA);
  const unsigned short* Bw = seg == 0 ? wq : (seg == 1 ? wk : wv);
  const float* bias        = seg == 0 ? bq : (seg == 1 ? bk : bv);

  const int tid = threadIdx.x;
  const int wave = tid >> 6, lane = tid & 63;
  const int wm = (wave >> 1) * 64, wn = (wave & 1) * 64;
  const int lr = lane & 15, lg = lane >> 4;
  const unsigned short* Ab = A + (size_t)my * 128 * DD;
  const unsigned short* Bb = Bw + (size_t)nx * 128 * DD;

  f4v z = {0.f, 0.f, 0.f, 0.f};
  f4v acc[4][4];
  for (int mi = 0; mi < 4; mi++) for (int ni = 0; ni < 4; ni++) acc[mi][ni] = z;

  for (int k0 = 0; k0 < DD; k0 += 64) {
    __syncthreads();
    for (int i = 0; i < 4; i++) {
      int c = tid + i * 256;
      int row = c >> 3, kc = (c & 7) << 3;
      load_lds16(Ab + (size_t)row * DD + k0 + kc, As + c * 8);
      load_lds16(Bb + (size_t)row * DD + k0 + kc, Bs + c * 8);
    }
    __syncthreads();
    for (int kk = 0; kk < 64; kk += 32) {
      s8v af[4], bf[4];
      for (int i = 0; i < 4; i++)
        af[i] = *(const s8v*)(As + (wm + i * 16 + lr) * 64 + kk + lg * 8);
      for (int i = 0; i < 4; i++)
        bf[i] = *(const s8v*)(Bs + (wn + i * 16 + lr) * 64 + kk + lg * 8);
      for (int mi = 0; mi < 4; mi++)
        for (int ni = 0; ni < 4; ni++)
          acc[mi][ni] = __builtin_amdgcn_mfma_f32_16x16x32_bf16(af[mi], bf[ni], acc[mi][ni], 0, 0, 0);
    }
  }
  if (seg < 2) {
    unsigned short* Cout = seg == 0 ? Qp : Kp;
    for (int ni = 0; ni < 4; ni++) {
      int col = nx * 128 + wn + ni * 16 + lr;
      float bv = bias[col];
      for (int mi = 0; mi < 4; mi++) {
        int row0 = my * 128 + wm + mi * 16 + lg * 4;
        for (int r = 0; r < 4; r++)
          Cout[(size_t)(row0 + r) * DD + col] = f2bf(acc[mi][ni][r] + bv);
      }
    }
  } else {
    // V: transposed store VpT[bh][d][l], 4 seq-consecutive rows per 8B store
    for (int ni = 0; ni < 4; ni++) {
      int col = nx * 128 + wn + ni * 16 + lr;
      float bv = bias[col];
      int hh = col >> 6, dd = col & 63;
      for (int mi = 0; mi < 4; mi++) {
        int row0 = my * 128 + wm + mi * 16 + lg * 4;
        int bb = row0 >> 11, ll = row0 & 2047;
        uint64_t w = 0;
        for (int r = 0; r < 4; r++)
          w |= (uint64_t)f2bf(acc[mi][ni][r] + bv) << (16 * r);
        *(uint64_t*)(VpT + ((size_t)(bb * NH + hh) * 64 + dd) * SEQ + ll) = w;
      }
    }
  }
}

// ---------------- causal flash attention (paired Q-tiles, static max) -------
#define KS_STRIDE 72
#define VT_STRIDE 136
#define PS_STRIDE 72

__device__ __forceinline__ void attn_step(
    const s8v (&qf)[2][2], const s8v (&kf)[2][4],
    f4v (&o)[2][4], float (&ls)[2][4],
    int qbase, int colbase,
    const short* __restrict__ Vt, int vsub, short* __restrict__ Pw,
    int lr, int lg)
{
  const float csc = 0.125f * 1.44269504089f;
  const float FM = 14.0f;
  f4v zv = {0.f, 0.f, 0.f, 0.f};
  f4v s[2][4];
  for (int mi = 0; mi < 2; mi++) for (int ni = 0; ni < 4; ni++) s[mi][ni] = zv;
  for (int ks = 0; ks < 2; ks++)
    for (int mi = 0; mi < 2; mi++)
      for (int ni = 0; ni < 4; ni++)
        s[mi][ni] = __builtin_amdgcn_mfma_f32_16x16x32_bf16(qf[mi][ks], kf[ks][ni], s[mi][ni], 0, 0, 0);
  const bool diag = (colbase + 63 > qbase);
  for (int mi = 0; mi < 2; mi++)
    for (int ni = 0; ni < 4; ni++)
      for (int r = 0; r < 4; r++) {
        float e = __builtin_amdgcn_exp2f(fmaf(s[mi][ni][r], csc, -FM));
        if (diag) {
          int row = qbase + mi * 16 + lg * 4 + r;
          int col = colbase + ni * 16 + lr;
          e = (col > row) ? 0.f : e;
        }
        ls[mi][r] += e;
        Pw[(mi * 16 + lg * 4 + r) * PS_STRIDE + ni * 16 + lr] = (short)f2bf_trunc(e);
      }
  for (int kc2 = 0; kc2 < 2; kc2++) {
    s8v pf[2], vf[4];
    for (int mi = 0; mi < 2; mi++)
      pf[mi] = *(const s8v*)(Pw + (mi * 16 + lr) * PS_STRIDE + kc2 * 32 + lg * 8);
    for (int ni = 0; ni < 4; ni++)
      vf[ni] = *(const s8v*)(Vt + (ni * 16 + lr) * VT_STRIDE + vsub + kc2 * 32 + lg * 8);
    for (int mi = 0; mi < 2; mi++)
      for (int ni = 0; ni < 4; ni++)
        o[mi][ni] = __builtin_amdgcn_mfma_f32_16x16x32_bf16(pf[mi], vf[ni], o[mi][ni], 0, 0, 0);
  }
}

__global__ __launch_bounds__(256, 2) void fattn(
    const unsigned short* __restrict__ Qp,
    const unsigned short* __restrict__ Kp,
    const unsigned short* __restrict__ VpT,
    unsigned short* __restrict__ Op)
{
  __shared__ __align__(16) short Ks[128 * KS_STRIDE];
  __shared__ __align__(16) short Vt[64 * VT_STRIDE];
  __shared__ __align__(16) short Ps[4 * 32 * PS_STRIDE];
  const int tid = threadIdx.x;
  const int wave = tid >> 6, lane = tid & 63;
  const int lr = lane & 15, lg = lane >> 4;
  // swizzle: XCD = linear%8 = bh%8 -> the 8 blocks of a head share an XCD L2
  const int linear = blockIdx.y * 8 + blockIdx.x;
  const int xA = linear >> 6;        // 0..7
  const int bh = linear & 63;        // 0..63
  const int b = bh >> 4, h = bh & 15;
  const int xB = NT - 1 - xA;
  const int qbA = xA * 128 + wave * 32;
  const int qbB = xB * 128 + wave * 32;
  const unsigned short* Qrow = Qp + ((size_t)b * SEQ) * DD + h * DHEAD;
  const unsigned short* Krow = Kp + ((size_t)b * SEQ) * DD + h * DHEAD;
  const unsigned short* VT   = VpT + (size_t)bh * 64 * SEQ;
  short* Pw = Ps + wave * (32 * PS_STRIDE);

  s8v qfA[2][2], qfB[2][2];
  for (int mi = 0; mi < 2; mi++)
    for (int ks = 0; ks < 2; ks++) {
      qfA[mi][ks] = *(const s8v*)(Qrow + (size_t)(qbA + mi * 16 + lr) * DD + ks * 32 + lg * 8);
      qfB[mi][ks] = *(const s8v*)(Qrow + (size_t)(qbB + mi * 16 + lr) * DD + ks * 32 + lg * 8);
    }

  f4v zv = {0.f, 0.f, 0.f, 0.f};
  f4v oA[2][4], oB[2][4];
  float lA[2][4], lB[2][4];
  for (int mi = 0; mi < 2; mi++)
    for (int r = 0; r < 4; r++) { lA[mi][r] = 0.f; lB[mi][r] = 0.f; }
  for (int mi = 0; mi < 2; mi++)
    for (int ni = 0; ni < 4; ni++) { oA[mi][ni] = zv; oB[mi][ni] = zv; }

  const int npair = xB + 1;

  for (int p = 0; p < npair; p++) {
    s8v kreg[4], vreg[4];
    int krow[4], kkc[4], vd[4], vkc[4];
    for (int i = 0; i < 4; i++) {
      int c = tid + i * 256;
      krow[i] = c >> 3; kkc[i] = (c & 7) << 3;
      kreg[i] = *(const s8v*)(Krow + (size_t)(p * 128 + krow[i]) * DD + kkc[i]);
      vd[i] = c >> 4; vkc[i] = (c & 15) << 3;
      vreg[i] = *(const s8v*)(VT + (size_t)vd[i] * SEQ + p * 128 + vkc[i]);
    }
    __syncthreads();
    for (int i = 0; i < 4; i++) {
      *(s8v*)(Ks + krow[i] * KS_STRIDE + kkc[i]) = kreg[i];
      *(s8v*)(Vt + vd[i] * VT_STRIDE + vkc[i]) = vreg[i];
    }
    __syncthreads();
    for (int sub = 0; sub < 2; sub++) {
      int colbase = (2 * p + sub) * 64;
      bool actB = colbase <= qbB + 31;
      bool actA = colbase <= qbA + 31;
      if (actB || actA) {
        const short* KsSub = Ks + sub * 64 * KS_STRIDE;
        s8v kf[2][4];
        for (int ks = 0; ks < 2; ks++)
          for (int ni = 0; ni < 4; ni++)
            kf[ks][ni] = *(const s8v*)(KsSub + (ni * 16 + lr) * KS_STRIDE + ks * 32 + lg * 8);
        int vsub = sub * 64;
        if (actB) attn_step(qfB, kf, oB, lB, qbB, colbase, Vt, vsub, Pw, lr, lg);
        if (actA) attn_step(qfA, kf, oA, lA, qbA, colbase, Vt, vsub, Pw, lr, lg);
      }
    }
  }

  unsigned short* Orow = Op + ((size_t)b * SEQ) * DD + h * DHEAD;
  for (int mi = 0; mi < 2; mi++)
    for (int r = 0; r < 4; r++) {
      float sA = lA[mi][r], sB = lB[mi][r];
      for (int d2 = 1; d2 < 16; d2 <<= 1) {
        sA += __shfl_xor(sA, d2);
        sB += __shfl_xor(sB, d2);
      }
      float invA = 1.f / sA, invB = 1.f / sB;
      size_t rowA = (size_t)qbA + mi * 16 + lg * 4 + r;
      size_t rowB = (size_t)qbB + mi * 16 + lg * 4 + r;
      for (int ni = 0; ni < 4; ni++) {
        Orow[rowA * DD + ni * 16 + lr] = f2bf(oA[mi][ni][r] * invA);
        Orow[rowB * DD + ni * 16 + lr] = f2bf(oB[mi][ni][r] * invB);
      }
    }
}

// ---------------- launcher ----------------
extern "C" void kernel_launch(void* const* d_in, const int* in_sizes, int n_in,
                              void* d_out, int out_size, void* d_ws, size_t ws_size,
                              hipStream_t stream) {
  const float* q    = (const float*)d_in[0];
  const float* k    = (const float*)d_in[1];
  const float* v    = (const float*)d_in[2];
  const float* wq_w = (const float*)d_in[3];
  const float* wq_b = (const float*)d_in[4];
  const float* wk_w = (const float*)d_in[5];
  const float* wk_b = (const float*)d_in[6];
  const float* wv_w = (const float*)d_in[7];
  const float* wv_b = (const float*)d_in[8];
  const float* wo_w = (const float*)d_in[9];
  const float* wo_b = (const float*)d_in[10];

  const size_t BIG = (size_t)MR * DD;
  const size_t WSZ = (size_t)DD * DD;
  unsigned short* p = (unsigned short*)d_ws;
  unsigned short* qb  = p; p += BIG;
  unsigned short* kb  = p; p += BIG;
  unsigned short* vb  = p; p += BIG;
  unsigned short* wqb = p; p += WSZ;
  unsigned short* wkb = p; p += WSZ;
  unsigned short* wvb = p; p += WSZ;
  unsigned short* wob = p; p += WSZ;
  unsigned short* Qp  = p; p += BIG;
  unsigned short* Kp  = p; p += BIG;
  unsigned short* VpT = p; p += BIG;   // [bh][64][SEQ]
  unsigned short* AO  = p; p += BIG;

  cvt_all<<<dim3(14336), dim3(256), 0, stream>>>(
      q, k, v, wq_w, wk_w, wv_w, wo_w, qb, kb, vb, wqb, wkb, wvb, wob);

  gemm_qkv<<<dim3(24, MR / 128), dim3(256), 0, stream>>>(
      qb, kb, vb, wqb, wkb, wvb, wq_b, wk_b, wv_b, Qp, Kp, VpT);

  fattn<<<dim3(NT / 2, NB * NH), dim3(256), 0, stream>>>(Qp, Kp, VpT, AO);

  gemm_bt<<<dim3(8, 128), dim3(256), 0, stream>>>(AO, wob, wo_b, (float*)d_out);

  (void)in_sizes; (void)n_in; (void)out_size; (void)ws_size;
}

// Round 5
// 325.377 us; speedup vs baseline: 1.7012x; 1.0046x over previous
//
#include <hip/hip_runtime.h>
#include <stdint.h>

#define DD 1024      // model dim
#define NH 16        // heads
#define DHEAD 64     // head dim
#define NB 4         // batch
#define SEQ 2048     // seq len
#define MR (NB*SEQ)  // 8192 rows
#define NT (SEQ/128) // 16 Q-tiles of 128 rows

typedef __attribute__((ext_vector_type(8))) short s8v;
typedef __attribute__((ext_vector_type(4))) float f4v;

__device__ __forceinline__ unsigned short f2bf(float f) {
  union { float f; uint32_t u; } c; c.f = f;
  uint32_t u = c.u;
  u += 0x7fffu + ((u >> 16) & 1u);   // RNE
  return (unsigned short)(u >> 16);
}
__device__ __forceinline__ unsigned short f2bf_trunc(float f) {
  union { float f; uint32_t u; } c; c.f = f;
  return (unsigned short)(c.u >> 16);
}

__device__ __forceinline__ void load_lds16(const void* g, void* lds) {
  __builtin_amdgcn_global_load_lds(
      (__attribute__((address_space(1))) void*)(uintptr_t)g,
      (__attribute__((address_space(3))) void*)(uint32_t)(uintptr_t)lds,
      16, 0, 0);
}

__device__ __forceinline__ s8v pack8(float4 a, float4 b) {
  union { unsigned short us[8]; s8v v; } t;
  t.us[0] = f2bf(a.x); t.us[1] = f2bf(a.y); t.us[2] = f2bf(a.z); t.us[3] = f2bf(a.w);
  t.us[4] = f2bf(b.x); t.us[5] = f2bf(b.y); t.us[6] = f2bf(b.z); t.us[7] = f2bf(b.w);
  return t.v;
}

// ---------------- fp32 -> bf16 convert, weights only (4 x 1M elems) ---------
__global__ void cvt_w(
    const float* __restrict__ w0, const float* __restrict__ w1,
    const float* __restrict__ w2, const float* __restrict__ w3,
    unsigned short* __restrict__ d0, unsigned short* __restrict__ d1,
    unsigned short* __restrict__ d2, unsigned short* __restrict__ d3)
{
  int blk = blockIdx.x;
  int a = blk >> 9;
  const float* src = a == 0 ? w0 : (a == 1 ? w1 : (a == 2 ? w2 : w3));
  unsigned short* dst = a == 0 ? d0 : (a == 1 ? d1 : (a == 2 ? d2 : d3));
  size_t i = (size_t)(blk & 511) * 2048 + (size_t)threadIdx.x * 8;
  float4 a4 = *(const float4*)(src + i);
  float4 b4 = *(const float4*)(src + i + 4);
  union { unsigned short us[8]; uint4 u; } t;
  t.us[0] = f2bf(a4.x); t.us[1] = f2bf(a4.y); t.us[2] = f2bf(a4.z); t.us[3] = f2bf(a4.w);
  t.us[4] = f2bf(b4.x); t.us[5] = f2bf(b4.y); t.us[6] = f2bf(b4.z); t.us[7] = f2bf(b4.w);
  *(uint4*)(dst + i) = t.u;
}

// ---------------- output projection GEMM: 64x128 tiles, swizzled LDS --------
// C[m,n] = sum_k A[m,k]*B[n,k] + bias[n], fp32 out. 1024 blocks.
// LDS granule swizzle: physical granule = logical ^ (row&7); staged via
// source-permuted global_load_lds; read side uses row&7 == lr&7.
__global__ __launch_bounds__(256, 2) void gemm_bt(
    const unsigned short* __restrict__ A,
    const unsigned short* __restrict__ Bw,
    const float* __restrict__ bias,
    float* __restrict__ Cout)
{
  __shared__ __align__(16) short As[64 * 64];
  __shared__ __align__(16) short Bs[128 * 64];
  const int linear = blockIdx.y * 8 + blockIdx.x;
  const int nx = linear >> 7;        // 0..7 weight column tile
  const int my = linear & 127;       // 0..127 M tile (64 rows); XCD = my%8
  const int tid = threadIdx.x;
  const int wave = tid >> 6, lane = tid & 63;
  const int wm = (wave >> 1) * 32, wn = (wave & 1) * 64;
  const int lr = lane & 15, lg = lane >> 4;
  const int sw = lr & 7;             // read-side swizzle key
  const unsigned short* Ab = A + (size_t)my * 64 * DD;
  const unsigned short* Bb = Bw + (size_t)nx * 128 * DD;

  f4v z = {0.f, 0.f, 0.f, 0.f};
  f4v acc[2][4];
  for (int mi = 0; mi < 2; mi++) for (int ni = 0; ni < 4; ni++) acc[mi][ni] = z;

  for (int k0 = 0; k0 < DD; k0 += 64) {
    __syncthreads();
    for (int i = 0; i < 2; i++) {
      int c = tid + i * 256;
      int row = c >> 3, pg = c & 7;
      load_lds16(Ab + (size_t)row * DD + k0 + ((pg ^ (row & 7)) << 3), As + c * 8);
    }
    for (int i = 0; i < 4; i++) {
      int c = tid + i * 256;
      int row = c >> 3, pg = c & 7;
      load_lds16(Bb + (size_t)row * DD + k0 + ((pg ^ (row & 7)) << 3), Bs + c * 8);
    }
    __syncthreads();
    for (int kk = 0; kk < 64; kk += 32) {
      int gb = kk >> 3;   // 0 or 4
      s8v af[2], bf[4];
      for (int i = 0; i < 2; i++)
        af[i] = *(const s8v*)(As + (wm + i * 16 + lr) * 64 + (((gb + lg) ^ sw) << 3));
      for (int i = 0; i < 4; i++)
        bf[i] = *(const s8v*)(Bs + (wn + i * 16 + lr) * 64 + (((gb + lg) ^ sw) << 3));
      for (int mi = 0; mi < 2; mi++)
        for (int ni = 0; ni < 4; ni++)
          acc[mi][ni] = __builtin_amdgcn_mfma_f32_16x16x32_bf16(af[mi], bf[ni], acc[mi][ni], 0, 0, 0);
    }
  }
  for (int ni = 0; ni < 4; ni++) {
    int col = nx * 128 + wn + ni * 16 + lr;
    float bv = bias[col];
    for (int mi = 0; mi < 2; mi++) {
      int row0 = my * 64 + wm + mi * 16 + lg * 4;
      for (int r = 0; r < 4; r++)
        Cout[(size_t)(row0 + r) * DD + col] = acc[mi][ni][r] + bv;
    }
  }
}

// ---------------- fused QKV projection GEMM -------------------------------
// A read directly as fp32 (cvt fused into staging), swizzled LDS, reg prefetch.
// 1536 blocks; XCD = my%8 (A-tile co-readers share an XCD).
__global__ __launch_bounds__(256, 2) void gemm_qkv(
    const float* __restrict__ qA, const float* __restrict__ kA,
    const float* __restrict__ vA,
    const unsigned short* __restrict__ wq, const unsigned short* __restrict__ wk,
    const unsigned short* __restrict__ wv,
    const float* __restrict__ bq, const float* __restrict__ bk, const float* __restrict__ bv,
    unsigned short* __restrict__ Qp, unsigned short* __restrict__ Kp,
    unsigned short* __restrict__ VpT)
{
  __shared__ __align__(16) short As[128 * 64];
  __shared__ __align__(16) short Bs[128 * 64];
  const int linear = blockIdx.y * 24 + blockIdx.x;
  const int nx  = linear / 192;        // 0..7
  const int rem = linear % 192;
  const int seg = rem >> 6;            // 0..2
  const int my  = rem & 63;            // 0..63
  const float* A          = seg == 0 ? qA : (seg == 1 ? kA : vA);
  const unsigned short* Bw = seg == 0 ? wq : (seg == 1 ? wk : wv);
  const float* bias        = seg == 0 ? bq : (seg == 1 ? bk : bv);

  const int tid = threadIdx.x;
  const int wave = tid >> 6, lane = tid & 63;
  const int wm = (wave >> 1) * 64, wn = (wave & 1) * 64;
  const int lr = lane & 15, lg = lane >> 4;
  const int sw = lr & 7;
  const float* Ab = A + (size_t)my * 128 * DD;
  const unsigned short* Bb = Bw + (size_t)nx * 128 * DD;

  // per-thread A staging: 4 chunks; chunk c = tid + i*256 -> row=c>>3, g=c&7
  int arow[4], ag[4];
  s8v areg[4];
  for (int i = 0; i < 4; i++) {
    int c = tid + i * 256;
    arow[i] = c >> 3; ag[i] = c & 7;
  }
  // prologue: load k0=0 slab
  for (int i = 0; i < 4; i++) {
    const float* src = Ab + (size_t)arow[i] * DD + (ag[i] << 3);
    areg[i] = pack8(*(const float4*)src, *(const float4*)(src + 4));
  }

  f4v z = {0.f, 0.f, 0.f, 0.f};
  f4v acc[4][4];
  for (int mi = 0; mi < 4; mi++) for (int ni = 0; ni < 4; ni++) acc[mi][ni] = z;

  for (int k0 = 0; k0 < DD; k0 += 64) {
    __syncthreads();   // prev compute done (also drains prefetch loads)
    // A: swizzled ds_write of converted regs
    for (int i = 0; i < 4; i++)
      *(s8v*)(As + arow[i] * 64 + ((ag[i] ^ (arow[i] & 7)) << 3)) = areg[i];
    // B: async global->LDS, source-permuted
    for (int i = 0; i < 4; i++) {
      int c = tid + i * 256;
      int row = c >> 3, pg = c & 7;
      load_lds16(Bb + (size_t)row * DD + k0 + ((pg ^ (row & 7)) << 3), Bs + c * 8);
    }
    __syncthreads();   // LDS valid
    // prefetch next A slab (overlaps compute; drained at next barrier)
    if (k0 + 64 < DD) {
      for (int i = 0; i < 4; i++) {
        const float* src = Ab + (size_t)arow[i] * DD + k0 + 64 + (ag[i] << 3);
        areg[i] = pack8(*(const float4*)src, *(const float4*)(src + 4));
      }
    }
    for (int kk = 0; kk < 64; kk += 32) {
      int gb = kk >> 3;
      s8v af[4], bf[4];
      for (int i = 0; i < 4; i++)
        af[i] = *(const s8v*)(As + (wm + i * 16 + lr) * 64 + (((gb + lg) ^ sw) << 3));
      for (int i = 0; i < 4; i++)
        bf[i] = *(const s8v*)(Bs + (wn + i * 16 + lr) * 64 + (((gb + lg) ^ sw) << 3));
      for (int mi = 0; mi < 4; mi++)
        for (int ni = 0; ni < 4; ni++)
          acc[mi][ni] = __builtin_amdgcn_mfma_f32_16x16x32_bf16(af[mi], bf[ni], acc[mi][ni], 0, 0, 0);
    }
  }
  if (seg < 2) {
    unsigned short* Cout = seg == 0 ? Qp : Kp;
    for (int ni = 0; ni < 4; ni++) {
      int col = nx * 128 + wn + ni * 16 + lr;
      float bv = bias[col];
      for (int mi = 0; mi < 4; mi++) {
        int row0 = my * 128 + wm + mi * 16 + lg * 4;
        for (int r = 0; r < 4; r++)
          Cout[(size_t)(row0 + r) * DD + col] = f2bf(acc[mi][ni][r] + bv);
      }
    }
  } else {
    // V: transposed store VpT[bh][d][l], 4 seq-consecutive rows per 8B store
    for (int ni = 0; ni < 4; ni++) {
      int col = nx * 128 + wn + ni * 16 + lr;
      float bv = bias[col];
      int hh = col >> 6, dd = col & 63;
      for (int mi = 0; mi < 4; mi++) {
        int row0 = my * 128 + wm + mi * 16 + lg * 4;
        int bb = row0 >> 11, ll = row0 & 2047;
        uint64_t w = 0;
        for (int r = 0; r < 4; r++)
          w |= (uint64_t)f2bf(acc[mi][ni][r] + bv) << (16 * r);
        *(uint64_t*)(VpT + ((size_t)(bb * NH + hh) * 64 + dd) * SEQ + ll) = w;
      }
    }
  }
}

// ---------------- causal flash attention (paired Q-tiles, static max) -------
#define KS_STRIDE 72
#define VT_STRIDE 136
#define PS_STRIDE 72

__device__ __forceinline__ void attn_step(
    const s8v (&qf)[2][2], const s8v (&kf)[2][4],
    f4v (&o)[2][4], float (&ls)[2][4],
    int qbase, int colbase,
    const short* __restrict__ Vt, int vsub, short* __restrict__ Pw,
    int lr, int lg)
{
  const float csc = 0.125f * 1.44269504089f;
  const float FM = 14.0f;
  f4v zv = {0.f, 0.f, 0.f, 0.f};
  f4v s[2][4];
  for (int mi = 0; mi < 2; mi++) for (int ni = 0; ni < 4; ni++) s[mi][ni] = zv;
  for (int ks = 0; ks < 2; ks++)
    for (int mi = 0; mi < 2; mi++)
      for (int ni = 0; ni < 4; ni++)
        s[mi][ni] = __builtin_amdgcn_mfma_f32_16x16x32_bf16(qf[mi][ks], kf[ks][ni], s[mi][ni], 0, 0, 0);
  const bool diag = (colbase + 63 > qbase);
  for (int mi = 0; mi < 2; mi++)
    for (int ni = 0; ni < 4; ni++)
      for (int r = 0; r < 4; r++) {
        float e = __builtin_amdgcn_exp2f(fmaf(s[mi][ni][r], csc, -FM));
        if (diag) {
          int row = qbase + mi * 16 + lg * 4 + r;
          int col = colbase + ni * 16 + lr;
          e = (col > row) ? 0.f : e;
        }
        ls[mi][r] += e;
        Pw[(mi * 16 + lg * 4 + r) * PS_STRIDE + ni * 16 + lr] = (short)f2bf_trunc(e);
      }
  for (int kc2 = 0; kc2 < 2; kc2++) {
    s8v pf[2], vf[4];
    for (int mi = 0; mi < 2; mi++)
      pf[mi] = *(const s8v*)(Pw + (mi * 16 + lr) * PS_STRIDE + kc2 * 32 + lg * 8);
    for (int ni = 0; ni < 4; ni++)
      vf[ni] = *(const s8v*)(Vt + (ni * 16 + lr) * VT_STRIDE + vsub + kc2 * 32 + lg * 8);
    for (int mi = 0; mi < 2; mi++)
      for (int ni = 0; ni < 4; ni++)
        o[mi][ni] = __builtin_amdgcn_mfma_f32_16x16x32_bf16(pf[mi], vf[ni], o[mi][ni], 0, 0, 0);
  }
}

__global__ __launch_bounds__(256, 2) void fattn(
    const unsigned short* __restrict__ Qp,
    const unsigned short* __restrict__ Kp,
    const unsigned short* __restrict__ VpT,
    unsigned short* __restrict__ Op)
{
  __shared__ __align__(16) short Ks[128 * KS_STRIDE];
  __shared__ __align__(16) short Vt[64 * VT_STRIDE];
  __shared__ __align__(16) short Ps[4 * 32 * PS_STRIDE];
  const int tid = threadIdx.x;
  const int wave = tid >> 6, lane = tid & 63;
  const int lr = lane & 15, lg = lane >> 4;
  const int linear = blockIdx.y * 8 + blockIdx.x;
  const int xA = linear >> 6;        // 0..7 ; XCD = bh%8
  const int bh = linear & 63;        // 0..63
  const int b = bh >> 4, h = bh & 15;
  const int xB = NT - 1 - xA;
  const int qbA = xA * 128 + wave * 32;
  const int qbB = xB * 128 + wave * 32;
  const unsigned short* Qrow = Qp + ((size_t)b * SEQ) * DD + h * DHEAD;
  const unsigned short* Krow = Kp + ((size_t)b * SEQ) * DD + h * DHEAD;
  const unsigned short* VT   = VpT + (size_t)bh * 64 * SEQ;
  short* Pw = Ps + wave * (32 * PS_STRIDE);

  s8v qfA[2][2], qfB[2][2];
  for (int mi = 0; mi < 2; mi++)
    for (int ks = 0; ks < 2; ks++) {
      qfA[mi][ks] = *(const s8v*)(Qrow + (size_t)(qbA + mi * 16 + lr) * DD + ks * 32 + lg * 8);
      qfB[mi][ks] = *(const s8v*)(Qrow + (size_t)(qbB + mi * 16 + lr) * DD + ks * 32 + lg * 8);
    }

  f4v zv = {0.f, 0.f, 0.f, 0.f};
  f4v oA[2][4], oB[2][4];
  float lA[2][4], lB[2][4];
  for (int mi = 0; mi < 2; mi++)
    for (int r = 0; r < 4; r++) { lA[mi][r] = 0.f; lB[mi][r] = 0.f; }
  for (int mi = 0; mi < 2; mi++)
    for (int ni = 0; ni < 4; ni++) { oA[mi][ni] = zv; oB[mi][ni] = zv; }

  const int npair = xB + 1;

  for (int p = 0; p < npair; p++) {
    s8v kreg[4], vreg[4];
    int krow[4], kkc[4], vd[4], vkc[4];
    for (int i = 0; i < 4; i++) {
      int c = tid + i * 256;
      krow[i] = c >> 3; kkc[i] = (c & 7) << 3;
      kreg[i] = *(const s8v*)(Krow + (size_t)(p * 128 + krow[i]) * DD + kkc[i]);
      vd[i] = c >> 4; vkc[i] = (c & 15) << 3;
      vreg[i] = *(const s8v*)(VT + (size_t)vd[i] * SEQ + p * 128 + vkc[i]);
    }
    __syncthreads();
    for (int i = 0; i < 4; i++) {
      *(s8v*)(Ks + krow[i] * KS_STRIDE + kkc[i]) = kreg[i];
      *(s8v*)(Vt + vd[i] * VT_STRIDE + vkc[i]) = vreg[i];
    }
    __syncthreads();
    for (int sub = 0; sub < 2; sub++) {
      int colbase = (2 * p + sub) * 64;
      bool actB = colbase <= qbB + 31;
      bool actA = colbase <= qbA + 31;
      if (actB || actA) {
        const short* KsSub = Ks + sub * 64 * KS_STRIDE;
        s8v kf[2][4];
        for (int ks = 0; ks < 2; ks++)
          for (int ni = 0; ni < 4; ni++)
            kf[ks][ni] = *(const s8v*)(KsSub + (ni * 16 + lr) * KS_STRIDE + ks * 32 + lg * 8);
        int vsub = sub * 64;
        if (actB) attn_step(qfB, kf, oB, lB, qbB, colbase, Vt, vsub, Pw, lr, lg);
        if (actA) attn_step(qfA, kf, oA, lA, qbA, colbase, Vt, vsub, Pw, lr, lg);
      }
    }
  }

  unsigned short* Orow = Op + ((size_t)b * SEQ) * DD + h * DHEAD;
  for (int mi = 0; mi < 2; mi++)
    for (int r = 0; r < 4; r++) {
      float sA = lA[mi][r], sB = lB[mi][r];
      for (int d2 = 1; d2 < 16; d2 <<= 1) {
        sA += __shfl_xor(sA, d2);
        sB += __shfl_xor(sB, d2);
      }
      float invA = 1.f / sA, invB = 1.f / sB;
      size_t rowA = (size_t)qbA + mi * 16 + lg * 4 + r;
      size_t rowB = (size_t)qbB + mi * 16 + lg * 4 + r;
      for (int ni = 0; ni < 4; ni++) {
        Orow[rowA * DD + ni * 16 + lr] = f2bf(oA[mi][ni][r] * invA);
        Orow[rowB * DD + ni * 16 + lr] = f2bf(oB[mi][ni][r] * invB);
      }
    }
}

// ---------------- launcher ----------------
extern "C" void kernel_launch(void* const* d_in, const int* in_sizes, int n_in,
                              void* d_out, int out_size, void* d_ws, size_t ws_size,
                              hipStream_t stream) {
  const float* q    = (const float*)d_in[0];
  const float* k    = (const float*)d_in[1];
  const float* v    = (const float*)d_in[2];
  const float* wq_w = (const float*)d_in[3];
  const float* wq_b = (const float*)d_in[4];
  const float* wk_w = (const float*)d_in[5];
  const float* wk_b = (const float*)d_in[6];
  const float* wv_w = (const float*)d_in[7];
  const float* wv_b = (const float*)d_in[8];
  const float* wo_w = (const float*)d_in[9];
  const float* wo_b = (const float*)d_in[10];

  const size_t BIG = (size_t)MR * DD;
  const size_t WSZ = (size_t)DD * DD;
  unsigned short* p = (unsigned short*)d_ws;
  unsigned short* wqb = p; p += WSZ;
  unsigned short* wkb = p; p += WSZ;
  unsigned short* wvb = p; p += WSZ;
  unsigned short* wob = p; p += WSZ;
  unsigned short* Qp  = p; p += BIG;
  unsigned short* Kp  = p; p += BIG;
  unsigned short* VpT = p; p += BIG;   // [bh][64][SEQ]
  unsigned short* AO  = p; p += BIG;

  cvt_w<<<dim3(2048), dim3(256), 0, stream>>>(
      wq_w, wk_w, wv_w, wo_w, wqb, wkb, wvb, wob);

  gemm_qkv<<<dim3(24, MR / 128), dim3(256), 0, stream>>>(
      q, k, v, wqb, wkb, wvb, wq_b, wk_b, wv_b, Qp, Kp, VpT);

  fattn<<<dim3(NT / 2, NB * NH), dim3(256), 0, stream>>>(Qp, Kp, VpT, AO);

  gemm_bt<<<dim3(8, 128), dim3(256), 0, stream>>>(AO, wob, wo_b, (float*)d_out);

  (void)in_sizes; (void)n_in; (void)out_size; (void)ws_size;
}